// Round 2
// baseline (221.894 us; speedup 1.0000x reference)
//
#include <hip/hip_runtime.h>

// InjectiveMapping: v[b,p,:] -> 10 layers of (4x4 matmul + bias + leaky_relu)
// with LIFO residual skips; plus per-(l,b) 4x4 determinant broadcast over P.
// L=10, B=16, P=200000, fp32. Memory-bound: ~51 MB read, ~180 MB write.
// Split: kernel A = transform (float4 in/out), kernel B = det slab fill
// (pure dwordx4 store stream, same shape as fillBufferAligned @6.7 TB/s).

constexpr int NL = 10;
constexpr int NB = 16;
constexpr int NP = 200000;
constexpr float SLOPE = 0.2f;

__device__ __forceinline__ float lrelu(float x) {
    return x > 0.0f ? x : SLOPE * x;
}

// ---------------- Kernel A: transform ----------------
__global__ __launch_bounds__(256) void transform_kernel(
    const float* __restrict__ vertices,   // [B, P, 4]
    const float* __restrict__ weights,    // [L, B, 20]
    float* __restrict__ out_v)            // [B, P, 4]
{
    const int b = blockIdx.y;             // block-uniform batch index
    const int p = blockIdx.x * blockDim.x + threadIdx.x;
    if (p >= NP) return;
    const int idx = b * NP + p;

    float4 vin = reinterpret_cast<const float4*>(vertices)[idx];
    float x0 = vin.x, x1 = vin.y, x2 = vin.z, x3 = vin.w;

    float res[4][4];                      // residual stack, registers

#pragma unroll
    for (int l = 0; l < NL; ++l) {
        // Uniform address -> scalar loads (SGPR weights).
        const float* m = weights + (l * NB + b) * 20;
        float y0 = fmaf(x3, m[12], m[16]);
        float y1 = fmaf(x3, m[13], m[17]);
        float y2 = fmaf(x3, m[14], m[18]);
        float y3 = fmaf(x3, m[15], m[19]);
        y0 = fmaf(x2, m[8],  y0);  y1 = fmaf(x2, m[9],  y1);
        y2 = fmaf(x2, m[10], y2);  y3 = fmaf(x2, m[11], y3);
        y0 = fmaf(x1, m[4],  y0);  y1 = fmaf(x1, m[5],  y1);
        y2 = fmaf(x1, m[6],  y2);  y3 = fmaf(x1, m[7],  y3);
        y0 = fmaf(x0, m[0],  y0);  y1 = fmaf(x0, m[1],  y1);
        y2 = fmaf(x0, m[2],  y2);  y3 = fmaf(x0, m[3],  y3);

        y0 = lrelu(y0); y1 = lrelu(y1); y2 = lrelu(y2); y3 = lrelu(y3);

        if (l < (NL - 1) / 2) {           // l = 0..3: push (post-relu)
            res[l][0] = y0; res[l][1] = y1; res[l][2] = y2; res[l][3] = y3;
        } else if (l > NL / 2) {          // l = 6..9: pop LIFO -> res[9-l]
            const int j = (NL - 1) - l;
            y0 += res[j][0]; y1 += res[j][1];
            y2 += res[j][2]; y3 += res[j][3];
        }
        x0 = y0; x1 = y1; x2 = y2; x3 = y3;
    }

    reinterpret_cast<float4*>(out_v)[idx] = make_float4(x0, x1, x2, x3);
}

// ---------------- Kernel B: det broadcast fill ----------------
// grid.y = l*NB + b (160 slabs); grid.x covers P/4 float4 groups per slab.
// All inputs uniform -> det computed from scalar loads; stores are
// block-contiguous dwordx4, the same stream shape as a buffer fill.
__global__ __launch_bounds__(256) void det_fill_kernel(
    const float* __restrict__ weights,    // [L, B, 20]
    float* __restrict__ out_det)          // [L, B, P]
{
    const int slab = blockIdx.y;          // l*NB + b, uniform
    const float* m = weights + slab * 20; // scalar loads

    float a00 = m[0],  a01 = m[1],  a02 = m[2],  a03 = m[3];
    float a10 = m[4],  a11 = m[5],  a12 = m[6],  a13 = m[7];
    float a20 = m[8],  a21 = m[9],  a22 = m[10], a23 = m[11];
    float a30 = m[12], a31 = m[13], a32 = m[14], a33 = m[15];
    float s0 = a00 * a11 - a01 * a10;
    float s1 = a00 * a12 - a02 * a10;
    float s2 = a00 * a13 - a03 * a10;
    float s3 = a01 * a12 - a02 * a11;
    float s4 = a01 * a13 - a03 * a11;
    float s5 = a02 * a13 - a03 * a12;
    float c5 = a22 * a33 - a23 * a32;
    float c4 = a21 * a33 - a23 * a31;
    float c3 = a21 * a32 - a22 * a31;
    float c2 = a20 * a33 - a23 * a30;
    float c1 = a20 * a32 - a22 * a30;
    float c0 = a20 * a31 - a21 * a30;
    float det = s0 * c5 - s1 * c4 + s2 * c3 + s3 * c2 - s4 * c1 + s5 * c0;

    const int g = blockIdx.x * blockDim.x + threadIdx.x;  // float4 group in slab
    if (g >= NP / 4) return;
    reinterpret_cast<float4*>(out_det)[slab * (NP / 4) + g] =
        make_float4(det, det, det, det);
}

extern "C" void kernel_launch(void* const* d_in, const int* in_sizes, int n_in,
                              void* d_out, int out_size, void* d_ws, size_t ws_size,
                              hipStream_t stream) {
    const float* vertices = (const float*)d_in[0];   // [16, 200000, 4]
    const float* weights  = (const float*)d_in[1];   // [10, 16, 20]
    float* out_v   = (float*)d_out;                  // first output: v
    float* out_det = (float*)d_out + NB * NP * 4;    // second: det_rep

    dim3 gridA((NP + 255) / 256, NB);
    transform_kernel<<<gridA, 256, 0, stream>>>(vertices, weights, out_v);

    dim3 gridB((NP / 4 + 255) / 256, NL * NB);
    det_fill_kernel<<<gridB, 256, 0, stream>>>(weights, out_det);
}

// Round 3
// 219.249 us; speedup vs baseline: 1.0121x; 1.0121x over previous
//
#include <hip/hip_runtime.h>

// InjectiveMapping: v[b,p,:] -> 10 layers of (4x4 matmul + bias + leaky_relu)
// with LIFO residual skips; plus per-(l,b) 4x4 determinant broadcast over P.
// L=10, B=16, P=200000, fp32. Memory floor: 51.2 MB read + 179.2 MB write
// = 230.4 MB -> ~35 us at 6.5 TB/s.
//
// Single fused kernel, x4 thread-coarsened along P:
//   - every global access is dwordx4 (4x float4 loads, 4x float4 v stores,
//     10x float4 det stores per thread)
//   - dets computed once per block by 10 lanes into LDS (weights are
//     block-uniform -> SGPR loads for the transform matrices)

constexpr int NL = 10;
constexpr int NB = 16;
constexpr int NP = 200000;
constexpr int NG = NP / 4;       // float4 groups per batch row
constexpr float SLOPE = 0.2f;

__device__ __forceinline__ float lrelu(float x) {
    return fmaxf(x, SLOPE * x);  // valid for slope in (0,1)
}

__global__ __launch_bounds__(256) void fused_kernel(
    const float* __restrict__ vertices,   // [B, P, 4]
    const float* __restrict__ weights,    // [L, B, 20]
    float* __restrict__ out_v,            // [B, P, 4]
    float* __restrict__ out_det)          // [L, B, P]
{
    const int b = blockIdx.y;             // block-uniform batch index

    // --- 10 dets for this b, once per block ---
    __shared__ float s_det[NL];
    if (threadIdx.x < NL) {
        const float* m = weights + (threadIdx.x * NB + b) * 20;
        float a00 = m[0],  a01 = m[1],  a02 = m[2],  a03 = m[3];
        float a10 = m[4],  a11 = m[5],  a12 = m[6],  a13 = m[7];
        float a20 = m[8],  a21 = m[9],  a22 = m[10], a23 = m[11];
        float a30 = m[12], a31 = m[13], a32 = m[14], a33 = m[15];
        float s0 = a00 * a11 - a01 * a10;
        float s1 = a00 * a12 - a02 * a10;
        float s2 = a00 * a13 - a03 * a10;
        float s3 = a01 * a12 - a02 * a11;
        float s4 = a01 * a13 - a03 * a11;
        float s5 = a02 * a13 - a03 * a12;
        float c5 = a22 * a33 - a23 * a32;
        float c4 = a21 * a33 - a23 * a31;
        float c3 = a21 * a32 - a22 * a31;
        float c2 = a20 * a33 - a23 * a30;
        float c1 = a20 * a32 - a22 * a30;
        float c0 = a20 * a31 - a21 * a30;
        s_det[threadIdx.x] = s0 * c5 - s1 * c4 + s2 * c3
                           + s3 * c2 - s4 * c1 + s5 * c0;
    }
    __syncthreads();

    const int g = blockIdx.x * blockDim.x + threadIdx.x;  // float4 group
    if (g >= NG) return;

    const float4* Vin  = reinterpret_cast<const float4*>(vertices);
    float4*       Vout = reinterpret_cast<float4*>(out_v);
    float4*       Dout = reinterpret_cast<float4*>(out_det);

    const int base = b * NP + 4 * g;      // float4 index of point 4g

    // state for 4 points: xs[point] = (x0,x1,x2,x3)
    float4 xs[4];
#pragma unroll
    for (int j = 0; j < 4; ++j) xs[j] = Vin[base + j];

    float res[4][4][4];                   // [stack][point][comp]

#pragma unroll
    for (int l = 0; l < NL; ++l) {
        const float* m = weights + (l * NB + b) * 20;  // uniform -> SGPRs
#pragma unroll
        for (int j = 0; j < 4; ++j) {
            float x0 = xs[j].x, x1 = xs[j].y, x2 = xs[j].z, x3 = xs[j].w;
            float y0 = fmaf(x3, m[12], m[16]);
            float y1 = fmaf(x3, m[13], m[17]);
            float y2 = fmaf(x3, m[14], m[18]);
            float y3 = fmaf(x3, m[15], m[19]);
            y0 = fmaf(x2, m[8],  y0);  y1 = fmaf(x2, m[9],  y1);
            y2 = fmaf(x2, m[10], y2);  y3 = fmaf(x2, m[11], y3);
            y0 = fmaf(x1, m[4],  y0);  y1 = fmaf(x1, m[5],  y1);
            y2 = fmaf(x1, m[6],  y2);  y3 = fmaf(x1, m[7],  y3);
            y0 = fmaf(x0, m[0],  y0);  y1 = fmaf(x0, m[1],  y1);
            y2 = fmaf(x0, m[2],  y2);  y3 = fmaf(x0, m[3],  y3);

            y0 = lrelu(y0); y1 = lrelu(y1); y2 = lrelu(y2); y3 = lrelu(y3);

            if (l < (NL - 1) / 2) {       // l = 0..3: push (post-relu)
                res[l][j][0] = y0; res[l][j][1] = y1;
                res[l][j][2] = y2; res[l][j][3] = y3;
            } else if (l > NL / 2) {      // l = 6..9: pop LIFO
                const int k = (NL - 1) - l;
                y0 += res[k][j][0]; y1 += res[k][j][1];
                y2 += res[k][j][2]; y3 += res[k][j][3];
            }
            xs[j] = make_float4(y0, y1, y2, y3);
        }
    }

#pragma unroll
    for (int j = 0; j < 4; ++j) Vout[base + j] = xs[j];

#pragma unroll
    for (int l = 0; l < NL; ++l) {
        const float d = s_det[l];
        Dout[(l * NB + b) * NG + g] = make_float4(d, d, d, d);
    }
}

extern "C" void kernel_launch(void* const* d_in, const int* in_sizes, int n_in,
                              void* d_out, int out_size, void* d_ws, size_t ws_size,
                              hipStream_t stream) {
    const float* vertices = (const float*)d_in[0];   // [16, 200000, 4]
    const float* weights  = (const float*)d_in[1];   // [10, 16, 20]
    float* out_v   = (float*)d_out;                  // first output: v
    float* out_det = (float*)d_out + NB * NP * 4;    // second: det_rep

    dim3 grid((NG + 255) / 256, NB);
    fused_kernel<<<grid, 256, 0, stream>>>(vertices, weights, out_v, out_det);
}